// Round 8
// baseline (112.066 us; speedup 1.0000x reference)
//
#include <hip/hip_runtime.h>
#include <stdint.h>

typedef _Float16 f16;
typedef __attribute__((ext_vector_type(8))) _Float16 f16x8;
typedef __attribute__((ext_vector_type(4))) float    f32x4;

constexpr int BROWS = 16384;

// ---- packed-weight layout in d_ws (f16 elements), transposed [N][K] ----
constexpr int OFF_CW1F = 0;                        // [272][480]: cW1 256 + fmW 16
constexpr int OFF_CW2  = OFF_CW1F + 272 * 480;     // [128][256]
constexpr int OFF_COW  = OFF_CW2  + 128 * 256;     // [512][128]
constexpr int OFF_EW1G = OFF_COW  + 512 * 128;     // e0:[272][480] (256+gateW 16), e1-3:[256][480]
constexpr int OFF_EW2  = OFF_EW1G + 1040 * 480;    // [512][256] (4 x 128)
constexpr int OFF_CTW  = OFF_EW2  + 512 * 256;     // [64][64]
constexpr int PACK_TOTAL = OFF_CTW + 64 * 64;      // 863,232 f16 = 1.73 MB

__device__ __forceinline__ void g2l16(const void* g, void* l) {
    __builtin_amdgcn_global_load_lds(
        (__attribute__((address_space(1))) void*)(void*)g,
        (__attribute__((address_space(3))) void*)l,
        16, 0, 0);
}

// ---------------------------------------------------------------------------
// Kernel 0: pack ALL weights to f16, transposed [N][K], zero-padded.
// ---------------------------------------------------------------------------
__global__ __launch_bounds__(256)
void pack_all(const float* __restrict__ cW1, const float* __restrict__ cW2,
              const float* __restrict__ coW, const float* __restrict__ expW1,
              const float* __restrict__ expW2, const float* __restrict__ fmW,
              const float* __restrict__ gateW, const float* __restrict__ contW,
              f16* __restrict__ wp)
{
    const int idx = blockIdx.x * 256 + threadIdx.x;
    if (idx >= PACK_TOTAL) return;
    float v = 0.f;
    if (idx < OFF_CW2) {                       // [272][480] cW1 + fmW
        const int l = idx, n = l / 480, k = l % 480;
        if (n < 256) { if (k < 464) v = cW1[k * 256 + n]; }
        else { const int c = n - 256; if (c < 10 && k < 464) v = fmW[k * 10 + c]; }
    } else if (idx < OFF_COW) {                // cW2 (256,128)
        const int l = idx - OFF_CW2, n = l / 256, k = l % 256;
        v = cW2[k * 128 + n];
    } else if (idx < OFF_EW1G) {               // coW (128,464), Npad 512
        const int l = idx - OFF_COW, n = l / 128, k = l % 128;
        if (n < 464) v = coW[k * 464 + n];
    } else if (idx < OFF_EW2) {                // expW1 + gateW fold
        const int l = idx - OFF_EW1G, n = l / 480, k = l % 480;
        if (n < 272) {                         // expert 0 block (+gates)
            if (n < 256) { if (k < 464) v = expW1[(long)k * 256 + n]; }
            else {
                const int c = n - 256;
                if (c < 12 && k < 464) v = gateW[((c >> 2) * 464 + k) * 4 + (c & 3)];
            }
        } else {
            const int m = n - 272, e = 1 + m / 256, nn = m % 256;
            if (k < 464) v = expW1[((long)e * 464 + k) * 256 + nn];
        }
    } else if (idx < OFF_CTW) {                // expW2 (4,256,128)
        const int l = idx - OFF_EW2, n = l / 256, k = l % 256;
        const int e = n >> 7, nn = n & 127;
        v = expW2[(e * 256 + k) * 128 + nn];
    } else {                                   // contW (64,64)
        const int l = idx - OFF_CTW, n = l / 64, k = l % 64;
        v = contW[k * 64 + n];
    }
    wp[idx] = (f16)v;
}

// ---------------------------------------------------------------------------
// stage one k-slab of B: NCOLS rows x 32 f16 (64 B rows) into LDS, lane-linear
// via global_load_lds width-16. slot sp -> (n = sp>>2, kchunk = sp&3).
// Bank-uniform on read: slot = 4n+g covers all 8 bank-groups evenly.
// ---------------------------------------------------------------------------
template<int NCOLS>
__device__ __forceinline__ void stage_slab(const f16* __restrict__ Bk, int ldb,
                                           f16* slab, int wave, int lane)
{
    constexpr int SLOTS = NCOLS * 4;
    constexpr int FULL  = SLOTS / 512;
    constexpr int REM   = SLOTS % 512;     // multiple of 64
#pragma unroll
    for (int p = 0; p < FULL; ++p) {
        const int sp = p * 512 + wave * 64 + lane;
        g2l16(Bk + (long)(sp >> 2) * ldb + (sp & 3) * 8,
              slab + (size_t)(p * 512 + wave * 64) * 8);
    }
    if constexpr (REM > 0) {
        if (wave < REM / 64) {
            const int sp = FULL * 512 + wave * 64 + lane;
            g2l16(Bk + (long)(sp >> 2) * ldb + (sp & 3) * 8,
                  slab + (size_t)(FULL * 512 + wave * 64) * 8);
        }
    }
}

// one k-step of MFMAs: af from As (LDS), bf from slab (LDS)
template<int MF, int NF, int LDA>
__device__ __forceinline__ void mfma_step(
    const f16* __restrict__ As, const f16* __restrict__ slab,
    int bcol0, int k0, f32x4 (&acc)[MF][NF], int g, int rr)
{
    f16x8 bf[NF];
#pragma unroll
    for (int j = 0; j < NF; ++j)
        bf[j] = *(const f16x8*)(slab + (size_t)((bcol0 + j * 16 + rr) * 4 + g) * 8);
#pragma unroll
    for (int i = 0; i < MF; ++i) {
        const f16x8 af = *(const f16x8*)(As + (size_t)(i * 16 + rr) * LDA + k0 + g * 8);
#pragma unroll
        for (int j = 0; j < NF; ++j)
            acc[i][j] = __builtin_amdgcn_mfma_f32_16x16x32_f16(
                af, bf[j], acc[i][j], 0, 0, 0);
    }
}

// double-buffered DMA pipeline: syncthreads (drains slab kb) -> issue kb+1 -> MFMA kb
template<int MF, int NF, int NCOLS, int KS, int LDA>
__device__ __forceinline__ void gemm_pipe(
    const f16* __restrict__ As, const f16* __restrict__ Bg, int ldb,
    f16* slab0, f16* slab1, int bcol0,
    f32x4 (&acc)[MF][NF], int wave, int lane)
{
    const int g = lane >> 4, rr = lane & 15;
    stage_slab<NCOLS>(Bg, ldb, slab0, wave, lane);
#pragma unroll
    for (int kb = 0; kb < KS; ++kb) {
        __syncthreads();                       // slab kb complete + everyone done with kb-1
        if (kb + 1 < KS)
            stage_slab<NCOLS>(Bg + (kb + 1) * 32, ldb,
                              (kb & 1) ? slab0 : slab1, wave, lane);
        mfma_step<MF, NF, LDA>(As, (kb & 1) ? slab1 : slab0, bcol0,
                               kb * 32, acc, g, rr);
    }
    __syncthreads();                           // protect last slab before reuse
}

// ---------------------------------------------------------------------------
// Kernel 1: entire MMoE forward. 64 rows/block, 256 blocks, 8 waves, ~154 KB LDS.
// ---------------------------------------------------------------------------
__global__ __launch_bounds__(512, 2)
void mmoe_fused(const int* __restrict__ disc, const float* __restrict__ cf,
                const float* __restrict__ e0p, const float* __restrict__ e1p,
                const float* __restrict__ e2p, const float* __restrict__ e3p,
                const float* __restrict__ e4p, const float* __restrict__ e5p,
                const float* __restrict__ e6p, const float* __restrict__ e7p,
                const float* __restrict__ contB, const float* __restrict__ cb1,
                const float* __restrict__ cb2, const float* __restrict__ cob,
                const float* __restrict__ expb1, const float* __restrict__ expb2,
                const float* __restrict__ gateB, const float* __restrict__ taskW,
                const float* __restrict__ taskB, const float* __restrict__ logv,
                const f16* __restrict__ wp, float* __restrict__ out)
{
    __shared__ __align__(16) f16 sh_x [64][488];   // x -> h (cols 464..487 zero)
    __shared__ __align__(16) f16 sh_c1[64][264];   // c1 / e1
    __shared__ __align__(16) f16 sh_c2[64][136];   // c2 (cf staging aliases)
    __shared__ __align__(16) f16 slab[2][272 * 32]; // B k-slab double buffer (17408 B ea)
    __shared__ float sh_g [64][12];
    __shared__ float sh_part[8][64][3];
    __shared__ float sh_fm[64];
    __shared__ const float* stabs[8];

    const int t = threadIdx.x;
    const int lane = t & 63, wave = t >> 6;        // 8 waves
    const int g = lane >> 4, rr = lane & 15;
    const long r0 = (long)blockIdx.x * 64;

    if (t == 0) {
        stabs[0] = e0p; stabs[1] = e1p; stabs[2] = e2p; stabs[3] = e3p;
        stabs[4] = e4p; stabs[5] = e5p; stabs[6] = e6p; stabs[7] = e7p;
    }
    __syncthreads();

    // ---- P0: zero pad, gather embeddings -> sh_x[:,0:400], cf -> cfp ----
    f16* cfp = (f16*)&sh_c2[0][0];                 // [64][72]
    for (int i = t; i < 64 * 24; i += 512) sh_x[i / 24][464 + i % 24] = (f16)0.f;
    {   // one (row, table) pair per thread: 64*8 = 512
        const int r = t >> 3, tab = t & 7;
        const long fi = disc[(r0 + r) * 8 + tab];
        const float* src = stabs[tab] + fi * 50;
        f16* dst = &sh_x[r][tab * 50];
#pragma unroll
        for (int q = 0; q < 25; ++q) {
            const float2 v = *(const float2*)(src + q * 2);
            dst[q * 2] = (f16)v.x; dst[q * 2 + 1] = (f16)v.y;
        }
    }
    for (int i = t; i < 64 * 16; i += 512) {       // cf f32 -> f16
        const int r = i >> 4, q = i & 15;
        const float4 v = *(const float4*)(cf + (r0 + r) * 64 + q * 4);
        f16* dst = cfp + r * 72 + q * 4;
        dst[0] = (f16)v.x; dst[1] = (f16)v.y; dst[2] = (f16)v.z; dst[3] = (f16)v.w;
    }
    __syncthreads();

    // ---- cont = relu(cf @ contW + b) -> sh_x[:,400:464] (direct, tiny) ----
    {
        const int wm = wave >> 2, wn = wave & 3;
        const f16* ctW = wp + OFF_CTW;
        f32x4 acc[2];
        acc[0] = (f32x4){0.f, 0.f, 0.f, 0.f}; acc[1] = acc[0];
#pragma unroll
        for (int kb = 0; kb < 2; ++kb) {
            const int ko = kb * 32 + g * 8;
            const f16x8 bfv = *(const f16x8*)(ctW + (size_t)(wn * 16 + rr) * 64 + ko);
#pragma unroll
            for (int i = 0; i < 2; ++i) {
                const f16x8 af = *(const f16x8*)(cfp + (size_t)(wm * 32 + i * 16 + rr) * 72 + ko);
                acc[i] = __builtin_amdgcn_mfma_f32_16x16x32_f16(af, bfv, acc[i], 0, 0, 0);
            }
        }
        const int col = wn * 16 + rr;
        const float bv = contB[col];
#pragma unroll
        for (int i = 0; i < 2; ++i)
#pragma unroll
            for (int rx = 0; rx < 4; ++rx)
                sh_x[wm * 32 + i * 16 + g * 4 + rx][400 + col] =
                    (f16)fmaxf(acc[i][rx] + bv, 0.f);
    }

    // ---- c1 + fm : pipe over [272][480] (cols 256-271 = fmW) ----
    {
        f32x4 acc[4][3] = {};
        gemm_pipe<4, 3, 272, 15, 488>(&sh_x[0][0], wp + OFF_CW1F, 480,
                                      slab[0], slab[1], wave * 32, acc, wave, lane);
#pragma unroll
        for (int j = 0; j < 2; ++j) {
            const int col = wave * 32 + j * 16 + rr;
            const float bv = cb1[col];
#pragma unroll
            for (int i = 0; i < 4; ++i)
#pragma unroll
                for (int rx = 0; rx < 4; ++rx)
                    sh_c1[i * 16 + g * 4 + rx][col] =
                        (f16)fmaxf(acc[i][j][rx] + bv, 0.f);
        }
        if (wave == 7) {     // j=2 -> xe cols 256..271 (10 real): fm
#pragma unroll
            for (int i = 0; i < 4; ++i)
#pragma unroll
                for (int rx = 0; rx < 4; ++rx) {
                    const float v = (rr < 10) ? acc[i][2][rx] : 0.f;
                    float s = v, ss = v * v;
#pragma unroll
                    for (int off = 1; off < 16; off <<= 1) {
                        s += __shfl_xor(s, off, 64); ss += __shfl_xor(ss, off, 64);
                    }
                    if (rr == 0)
                        sh_fm[i * 16 + g * 4 + rx] = 0.5f * (s * s - ss);
                }
        }
    }

    // ---- c2 = relu(c1 @ cW2 + cb2) ----
    {
        f32x4 acc[4][1] = {};
        gemm_pipe<4, 1, 128, 8, 264>(&sh_c1[0][0], wp + OFF_CW2, 256,
                                     slab[0], slab[1], wave * 16, acc, wave, lane);
        const int col = wave * 16 + rr;
        const float bv = cb2[col];
#pragma unroll
        for (int i = 0; i < 4; ++i)
#pragma unroll
            for (int rx = 0; rx < 4; ++rx)
                sh_c2[i * 16 + g * 4 + rx][col] =
                    (f16)fmaxf(acc[i][0][rx] + bv, 0.f);
    }

    // ---- h = x + (c2 @ coW + cob) + fm (two 256-col halves, in-place) ----
#pragma unroll 1
    for (int half = 0; half < 2; ++half) {
        f32x4 acc[4][2] = {};
        gemm_pipe<4, 2, 256, 4, 136>(&sh_c2[0][0], wp + OFF_COW + half * 256 * 128, 128,
                                     slab[0], slab[1], wave * 32, acc, wave, lane);
#pragma unroll
        for (int j = 0; j < 2; ++j) {
            const int col = half * 256 + wave * 32 + j * 16 + rr;
            if (col < 464) {
                const float bv = cob[col];
#pragma unroll
                for (int i = 0; i < 4; ++i)
#pragma unroll
                    for (int rx = 0; rx < 4; ++rx) {
                        const int row = i * 16 + g * 4 + rx;
                        const float v = acc[i][j][rx] + bv +
                                        (float)sh_x[row][col] + sh_fm[row];
                        sh_x[row][col] = (f16)v;
                    }
            }
        }
    }

    // ---- experts + gates; gates folded into e1[0] weight stream ----
    float tw[3];
#pragma unroll
    for (int tt = 0; tt < 3; ++tt) tw[tt] = taskW[tt * 128 + wave * 16 + rr];
    float oacc[4][4][3];
#pragma unroll
    for (int i = 0; i < 4; ++i)
#pragma unroll
        for (int rx = 0; rx < 4; ++rx)
#pragma unroll
            for (int tt = 0; tt < 3; ++tt) oacc[i][rx][tt] = 0.f;

#pragma unroll 1
    for (int e = 0; e < 4; ++e) {
        // e1[e] (+gates for e==0)
        if (e == 0) {
            f32x4 acc[4][3] = {};
            gemm_pipe<4, 3, 272, 15, 488>(&sh_x[0][0], wp + OFF_EW1G, 480,
                                          slab[0], slab[1], wave * 32, acc, wave, lane);
#pragma unroll
            for (int j = 0; j < 2; ++j) {
                const int col = wave * 32 + j * 16 + rr;
                const float bv = expb1[col];
#pragma unroll
                for (int i = 0; i < 4; ++i)
#pragma unroll
                    for (int rx = 0; rx < 4; ++rx)
                        sh_c1[i * 16 + g * 4 + rx][col] =
                            (f16)fmaxf(acc[i][j][rx] + bv, 0.f);
            }
            if (wave == 7) {   // gates: logits cols 256..267 -> softmax over e
                const float gb = (rr < 12) ? gateB[rr] : 0.f;
#pragma unroll
                for (int i = 0; i < 4; ++i)
#pragma unroll
                    for (int rx = 0; rx < 4; ++rx) {
                        const float v = acc[i][2][rx] + gb;
                        float m = fmaxf(v, __shfl_xor(v, 1, 64));
                        m = fmaxf(m, __shfl_xor(m, 2, 64));
                        const float p = __expf(v - m);
                        float s = p + __shfl_xor(p, 1, 64);
                        s += __shfl_xor(s, 2, 64);
                        if (rr < 12)
                            sh_g[i * 16 + g * 4 + rx][rr] = p / s;
                    }
            }
        } else {
            f32x4 acc[4][2] = {};
            gemm_pipe<4, 2, 256, 15, 488>(
                &sh_x[0][0], wp + OFF_EW1G + (size_t)(272 + (e - 1) * 256) * 480, 480,
                slab[0], slab[1], wave * 32, acc, wave, lane);
#pragma unroll
            for (int j = 0; j < 2; ++j) {
                const int col = wave * 32 + j * 16 + rr;
                const float bv = expb1[e * 256 + col];
#pragma unroll
                for (int i = 0; i < 4; ++i)
#pragma unroll
                    for (int rx = 0; rx < 4; ++rx)
                        sh_c1[i * 16 + g * 4 + rx][col] =
                            (f16)fmaxf(acc[i][j][rx] + bv, 0.f);
            }
        }
        // e2[e]: eo in regs -> gated per-lane accumulate (reduce deferred)
        {
            f32x4 acc[4][1] = {};
            gemm_pipe<4, 1, 128, 8, 264>(&sh_c1[0][0], wp + OFF_EW2 + (size_t)e * 128 * 256, 256,
                                         slab[0], slab[1], wave * 16, acc, wave, lane);
            const float bv = expb2[e * 128 + wave * 16 + rr];
#pragma unroll
            for (int i = 0; i < 4; ++i)
#pragma unroll
                for (int rx = 0; rx < 4; ++rx) {
                    const int row = i * 16 + g * 4 + rx;
                    const float v = acc[i][0][rx] + bv;
#pragma unroll
                    for (int tt = 0; tt < 3; ++tt)
                        oacc[i][rx][tt] += sh_g[row][tt * 4 + e] * (v * tw[tt]);
                }
        }
    }

    // ---- deferred 16-lane reduce, then cross-wave sum ----
#pragma unroll
    for (int i = 0; i < 4; ++i)
#pragma unroll
        for (int rx = 0; rx < 4; ++rx)
#pragma unroll
            for (int tt = 0; tt < 3; ++tt) {
                float s = oacc[i][rx][tt];
#pragma unroll
                for (int off = 1; off < 16; off <<= 1)
                    s += __shfl_xor(s, off, 64);
                if (rr == 0)
                    sh_part[wave][i * 16 + g * 4 + rx][tt] = s;
            }
    __syncthreads();
    if (t < 64 * 3) {
        const int row = t / 3, tt = t - row * 3;
        float s = taskB[tt];
#pragma unroll
        for (int w = 0; w < 8; ++w) s += sh_part[w][row][tt];
        out[(r0 + row) * 3 + tt] = s;
    }
    if (blockIdx.x == 0 && t < 3) out[(long)BROWS * 3 + t] = logv[t];
}

// ---------------------------------------------------------------------------
extern "C" void kernel_launch(void* const* d_in, const int* in_sizes, int n_in,
                              void* d_out, int out_size, void* d_ws, size_t ws_size,
                              hipStream_t stream)
{
    (void)in_sizes; (void)n_in; (void)out_size; (void)ws_size;

    const int*   disc  = (const int*)  d_in[0];
    const float* cf    = (const float*)d_in[1];
    const float* emb0  = (const float*)d_in[2];
    const float* emb1  = (const float*)d_in[3];
    const float* emb2  = (const float*)d_in[4];
    const float* emb3  = (const float*)d_in[5];
    const float* emb4  = (const float*)d_in[6];
    const float* emb5  = (const float*)d_in[7];
    const float* emb6  = (const float*)d_in[8];
    const float* emb7  = (const float*)d_in[9];
    const float* contW = (const float*)d_in[10];
    const float* contB = (const float*)d_in[11];
    const float* fmW   = (const float*)d_in[12];
    const float* cW1   = (const float*)d_in[13];
    const float* cb1   = (const float*)d_in[14];
    const float* cW2   = (const float*)d_in[15];
    const float* cb2   = (const float*)d_in[16];
    const float* coW   = (const float*)d_in[17];
    const float* cob   = (const float*)d_in[18];
    const float* expW1 = (const float*)d_in[19];
    const float* expb1 = (const float*)d_in[20];
    const float* expW2 = (const float*)d_in[21];
    const float* expb2 = (const float*)d_in[22];
    const float* gateW = (const float*)d_in[23];
    const float* gateB = (const float*)d_in[24];
    const float* taskW = (const float*)d_in[25];
    const float* taskB = (const float*)d_in[26];
    const float* logv  = (const float*)d_in[27];

    f16* wp = (f16*)d_ws;

    pack_all<<<(PACK_TOTAL + 255) / 256, 256, 0, stream>>>(
        cW1, cW2, coW, expW1, expW2, fmW, gateW, contW, wp);

    mmoe_fused<<<BROWS / 64, 512, 0, stream>>>(
        disc, cf, emb0, emb1, emb2, emb3, emb4, emb5, emb6, emb7,
        contB, cb1, cb2, cob, expb1, expb2, gateB, taskW, taskB, logv,
        wp, (float*)d_out);
}

// Round 9
// 107.732 us; speedup vs baseline: 1.0402x; 1.0402x over previous
//
#include <hip/hip_runtime.h>
#include <stdint.h>

typedef _Float16 f16;
typedef __attribute__((ext_vector_type(8))) _Float16 f16x8;
typedef __attribute__((ext_vector_type(4))) float    f32x4;

constexpr int BROWS = 16384;

// ---- packed-weight layout in d_ws (f16), SLAB order: [kb][slot=4n+c][8] ----
// slot sp holds W[k = kb*32 + (sp&3)*8 .. +8][n = sp>>2]  (transposed, 0-pad)
constexpr int OFF_CW1F = 0;                          // N=272,K=480 (cW1 256 + fmW)
constexpr int OFF_CW2  = OFF_CW1F + 272 * 480;       // N=128,K=256
constexpr int OFF_COW  = OFF_CW2  + 128 * 256;       // 2 halves, each N=256,K=128
constexpr int OFF_EW1G = OFF_COW  + 512 * 128;       // e0: N=272,K=480 (+gateW); e1-3: N=256,K=480
constexpr int OFF_EW2  = OFF_EW1G + (272 + 3 * 256) * 480; // 4 x (N=128,K=256)
constexpr int OFF_CTW  = OFF_EW2  + 4 * 128 * 256;   // [64][64] plain transposed
constexpr int PACK_TOTAL = OFF_CTW + 64 * 64;        // 863,232 f16 = 1.73 MB

__device__ __forceinline__ void g2l16(const void* g, void* l) {
    __builtin_amdgcn_global_load_lds(
        (__attribute__((address_space(1))) void*)(void*)g,
        (__attribute__((address_space(3))) void*)l,
        16, 0, 0);
}

// ---------------------------------------------------------------------------
// Kernel 0: pack ALL weights to f16 in slab order.
// ---------------------------------------------------------------------------
__global__ __launch_bounds__(256)
void pack_all(const float* __restrict__ cW1, const float* __restrict__ cW2,
              const float* __restrict__ coW, const float* __restrict__ expW1,
              const float* __restrict__ expW2, const float* __restrict__ fmW,
              const float* __restrict__ gateW, const float* __restrict__ contW,
              f16* __restrict__ wp)
{
    const int idx = blockIdx.x * 256 + threadIdx.x;
    if (idx >= PACK_TOTAL) return;
    float v = 0.f;

    auto decode = [](int l, int N, int& n, int& k) {
        const int kb = l / (N * 32); l -= kb * (N * 32);
        const int sp = l >> 3, q = l & 7;
        n = sp >> 2; k = kb * 32 + (sp & 3) * 8 + q;
    };

    if (idx < OFF_CW2) {                        // CW1F: N=272,K=480
        int n, k; decode(idx - OFF_CW1F, 272, n, k);
        if (n < 256) { if (k < 464) v = cW1[k * 256 + n]; }
        else { const int c = n - 256; if (c < 10 && k < 464) v = fmW[k * 10 + c]; }
    } else if (idx < OFF_COW) {                 // CW2: N=128,K=256
        int n, k; decode(idx - OFF_CW2, 128, n, k);
        v = cW2[k * 128 + n];
    } else if (idx < OFF_EW1G) {                // COW: 2 halves N=256,K=128
        int l = idx - OFF_COW;
        const int half = l / (256 * 128); l -= half * (256 * 128);
        int n, k; decode(l, 256, n, k);
        const int col = half * 256 + n;
        if (col < 464) v = coW[k * 464 + col];
    } else if (idx < OFF_EW2) {                 // EW1G
        int l = idx - OFF_EW1G;
        if (l < 272 * 480) {                    // expert 0 (+gates)
            int n, k; decode(l, 272, n, k);
            if (n < 256) { if (k < 464) v = expW1[(long)k * 256 + n]; }
            else {
                const int c = n - 256;
                if (c < 12 && k < 464) v = gateW[((c >> 2) * 464 + k) * 4 + (c & 3)];
            }
        } else {
            l -= 272 * 480;
            const int e = 1 + l / (256 * 480); l %= 256 * 480;
            int n, k; decode(l, 256, n, k);
            if (k < 464) v = expW1[((long)e * 464 + k) * 256 + n];
        }
    } else if (idx < OFF_CTW) {                 // EW2: 4 x N=128,K=256
        int l = idx - OFF_EW2;
        const int e = l / (128 * 256); l %= 128 * 256;
        int n, k; decode(l, 128, n, k);
        v = expW2[(e * 256 + k) * 128 + n];
    } else {                                    // CTW [64][64] transposed
        const int l = idx - OFF_CTW, n = l / 64, k = l % 64;
        v = contW[k * 64 + n];
    }
    wp[idx] = (f16)v;
}

// ---------------------------------------------------------------------------
// stage one pre-packed k-slab (NCOLS*32 f16, fully contiguous) into LDS.
// Per wave-instruction: 64 lanes x 16 B = 1 KB contiguous. Lane-linear dest.
// ---------------------------------------------------------------------------
template<int NCOLS>
__device__ __forceinline__ void stage_slab(const f16* __restrict__ Bk,
                                           f16* slab, int wave, int lane)
{
    constexpr int SLOTS = NCOLS * 4;
    constexpr int FULL  = SLOTS / 512;
    constexpr int REM   = SLOTS % 512;     // multiple of 64
#pragma unroll
    for (int p = 0; p < FULL; ++p) {
        const int sp = p * 512 + wave * 64 + lane;
        g2l16(Bk + (size_t)sp * 8, slab + (size_t)(p * 512 + wave * 64) * 8);
    }
    if constexpr (REM > 0) {
        if (wave < REM / 64) {
            const int sp = FULL * 512 + wave * 64 + lane;
            g2l16(Bk + (size_t)sp * 8, slab + (size_t)(FULL * 512 + wave * 64) * 8);
        }
    }
}

// one k-step of MFMAs: af from As (LDS), bf from slab (LDS)
template<int MF, int NF, int LDA>
__device__ __forceinline__ void mfma_step(
    const f16* __restrict__ As, const f16* __restrict__ slab,
    int bcol0, int k0, f32x4 (&acc)[MF][NF], int g, int rr)
{
    f16x8 bf[NF];
#pragma unroll
    for (int j = 0; j < NF; ++j)
        bf[j] = *(const f16x8*)(slab + (size_t)((bcol0 + j * 16 + rr) * 4 + g) * 8);
#pragma unroll
    for (int i = 0; i < MF; ++i) {
        const f16x8 af = *(const f16x8*)(As + (size_t)(i * 16 + rr) * LDA + k0 + g * 8);
#pragma unroll
        for (int j = 0; j < NF; ++j)
            acc[i][j] = __builtin_amdgcn_mfma_f32_16x16x32_f16(
                af, bf[j], acc[i][j], 0, 0, 0);
    }
}

// double-buffered DMA pipeline over pre-slabbed weights
template<int MF, int NF, int NCOLS, int KS, int LDA>
__device__ __forceinline__ void gemm_pipe(
    const f16* __restrict__ As, const f16* __restrict__ Bg,
    f16* slab0, f16* slab1, int bcol0,
    f32x4 (&acc)[MF][NF], int wave, int lane)
{
    const int g = lane >> 4, rr = lane & 15;
    stage_slab<NCOLS>(Bg, slab0, wave, lane);
#pragma unroll
    for (int kb = 0; kb < KS; ++kb) {
        __syncthreads();                       // slab kb landed; kb-1 consumers done
        if (kb + 1 < KS)
            stage_slab<NCOLS>(Bg + (size_t)(kb + 1) * NCOLS * 32,
                              (kb & 1) ? slab0 : slab1, wave, lane);
        mfma_step<MF, NF, LDA>(As, (kb & 1) ? slab1 : slab0, bcol0,
                               kb * 32, acc, g, rr);
    }
    __syncthreads();                           // protect last slab before reuse
}

// ---------------------------------------------------------------------------
// Kernel 1: entire MMoE forward. 64 rows/block, 256 blocks, 8 waves.
// ---------------------------------------------------------------------------
__global__ __launch_bounds__(512, 2)
void mmoe_fused(const int* __restrict__ disc, const float* __restrict__ cf,
                const float* __restrict__ e0p, const float* __restrict__ e1p,
                const float* __restrict__ e2p, const float* __restrict__ e3p,
                const float* __restrict__ e4p, const float* __restrict__ e5p,
                const float* __restrict__ e6p, const float* __restrict__ e7p,
                const float* __restrict__ contB, const float* __restrict__ cb1,
                const float* __restrict__ cb2, const float* __restrict__ cob,
                const float* __restrict__ expb1, const float* __restrict__ expb2,
                const float* __restrict__ gateB, const float* __restrict__ taskW,
                const float* __restrict__ taskB, const float* __restrict__ logv,
                const f16* __restrict__ wp, float* __restrict__ out)
{
    __shared__ __align__(16) f16 sh_x [64][488];    // x -> h (cols 464..487 zero)
    __shared__ __align__(16) f16 sh_c1[64][264];    // c1 / e1
    __shared__ __align__(16) f16 sh_c2[64][136];    // c2 (cf staging aliases)
    __shared__ __align__(16) f16 slab[2][272 * 32]; // B k-slab double buffer
    __shared__ float sh_g [64][12];
    __shared__ float sh_part[8][64][3];
    __shared__ float sh_fm[64];
    __shared__ const float* stabs[8];

    const int t = threadIdx.x;
    const int lane = t & 63, wave = t >> 6;         // 8 waves
    const int g = lane >> 4, rr = lane & 15;
    const long r0 = (long)blockIdx.x * 64;

    if (t == 0) {
        stabs[0] = e0p; stabs[1] = e1p; stabs[2] = e2p; stabs[3] = e3p;
        stabs[4] = e4p; stabs[5] = e5p; stabs[6] = e6p; stabs[7] = e7p;
    }
    __syncthreads();

    // ---- P0: zero pad, gather embeddings -> sh_x[:,0:400], cf -> cfp ----
    f16* cfp = (f16*)&sh_c2[0][0];                  // [64][72]
    for (int i = t; i < 64 * 24; i += 512) sh_x[i / 24][464 + i % 24] = (f16)0.f;
    {   // one (row, table) pair per thread: 64*8 = 512
        const int r = t >> 3, tab = t & 7;
        const long fi = disc[(r0 + r) * 8 + tab];
        const float* src = stabs[tab] + fi * 50;
        f16* dst = &sh_x[r][tab * 50];
#pragma unroll
        for (int q = 0; q < 25; ++q) {
            const float2 v = *(const float2*)(src + q * 2);
            dst[q * 2] = (f16)v.x; dst[q * 2 + 1] = (f16)v.y;
        }
    }
    for (int i = t; i < 64 * 16; i += 512) {        // cf f32 -> f16
        const int r = i >> 4, q = i & 15;
        const float4 v = *(const float4*)(cf + (r0 + r) * 64 + q * 4);
        f16* dst = cfp + r * 72 + q * 4;
        dst[0] = (f16)v.x; dst[1] = (f16)v.y; dst[2] = (f16)v.z; dst[3] = (f16)v.w;
    }
    __syncthreads();

    // ---- cont = relu(cf @ contW + b) -> sh_x[:,400:464] (direct, tiny) ----
    {
        const int wm = wave >> 2, wn = wave & 3;
        const f16* ctW = wp + OFF_CTW;
        f32x4 acc[2];
        acc[0] = (f32x4){0.f, 0.f, 0.f, 0.f}; acc[1] = acc[0];
#pragma unroll
        for (int kb = 0; kb < 2; ++kb) {
            const int ko = kb * 32 + g * 8;
            const f16x8 bfv = *(const f16x8*)(ctW + (size_t)(wn * 16 + rr) * 64 + ko);
#pragma unroll
            for (int i = 0; i < 2; ++i) {
                const f16x8 af = *(const f16x8*)(cfp + (size_t)(wm * 32 + i * 16 + rr) * 72 + ko);
                acc[i] = __builtin_amdgcn_mfma_f32_16x16x32_f16(af, bfv, acc[i], 0, 0, 0);
            }
        }
        const int col = wn * 16 + rr;
        const float bv = contB[col];
#pragma unroll
        for (int i = 0; i < 2; ++i)
#pragma unroll
            for (int rx = 0; rx < 4; ++rx)
                sh_x[wm * 32 + i * 16 + g * 4 + rx][400 + col] =
                    (f16)fmaxf(acc[i][rx] + bv, 0.f);
    }

    // ---- c1 + fm : pipe over N=272 (cols 256-271 = fmW) ----
    {
        f32x4 acc[4][3] = {};
        gemm_pipe<4, 3, 272, 15, 488>(&sh_x[0][0], wp + OFF_CW1F,
                                      slab[0], slab[1], wave * 32, acc, wave, lane);
#pragma unroll
        for (int j = 0; j < 2; ++j) {
            const int col = wave * 32 + j * 16 + rr;
            const float bv = cb1[col];
#pragma unroll
            for (int i = 0; i < 4; ++i)
#pragma unroll
                for (int rx = 0; rx < 4; ++rx)
                    sh_c1[i * 16 + g * 4 + rx][col] =
                        (f16)fmaxf(acc[i][j][rx] + bv, 0.f);
        }
        if (wave == 7) {     // j=2 -> xe cols 256..271 (10 real): fm
#pragma unroll
            for (int i = 0; i < 4; ++i)
#pragma unroll
                for (int rx = 0; rx < 4; ++rx) {
                    const float v = (rr < 10) ? acc[i][2][rx] : 0.f;
                    float s = v, ss = v * v;
#pragma unroll
                    for (int off = 1; off < 16; off <<= 1) {
                        s += __shfl_xor(s, off, 64); ss += __shfl_xor(ss, off, 64);
                    }
                    if (rr == 0)
                        sh_fm[i * 16 + g * 4 + rx] = 0.5f * (s * s - ss);
                }
        }
    }

    // ---- c2 = relu(c1 @ cW2 + cb2) ----
    {
        f32x4 acc[4][1] = {};
        gemm_pipe<4, 1, 128, 8, 264>(&sh_c1[0][0], wp + OFF_CW2,
                                     slab[0], slab[1], wave * 16, acc, wave, lane);
        const int col = wave * 16 + rr;
        const float bv = cb2[col];
#pragma unroll
        for (int i = 0; i < 4; ++i)
#pragma unroll
            for (int rx = 0; rx < 4; ++rx)
                sh_c2[i * 16 + g * 4 + rx][col] =
                    (f16)fmaxf(acc[i][0][rx] + bv, 0.f);
    }

    // ---- h = x + (c2 @ coW + cob) + fm (two pre-split N=256 halves) ----
#pragma unroll 1
    for (int half = 0; half < 2; ++half) {
        f32x4 acc[4][2] = {};
        gemm_pipe<4, 2, 256, 4, 136>(&sh_c2[0][0], wp + OFF_COW + (size_t)half * 256 * 128,
                                     slab[0], slab[1], wave * 32, acc, wave, lane);
#pragma unroll
        for (int j = 0; j < 2; ++j) {
            const int col = half * 256 + wave * 32 + j * 16 + rr;
            if (col < 464) {
                const float bv = cob[col];
#pragma unroll
                for (int i = 0; i < 4; ++i)
#pragma unroll
                    for (int rx = 0; rx < 4; ++rx) {
                        const int row = i * 16 + g * 4 + rx;
                        const float v = acc[i][j][rx] + bv +
                                        (float)sh_x[row][col] + sh_fm[row];
                        sh_x[row][col] = (f16)v;
                    }
            }
        }
    }

    // ---- experts + gates; gates folded into e1[0] weight stream ----
    float tw[3];
#pragma unroll
    for (int tt = 0; tt < 3; ++tt) tw[tt] = taskW[tt * 128 + wave * 16 + rr];
    float oacc[4][4][3];
#pragma unroll
    for (int i = 0; i < 4; ++i)
#pragma unroll
        for (int rx = 0; rx < 4; ++rx)
#pragma unroll
            for (int tt = 0; tt < 3; ++tt) oacc[i][rx][tt] = 0.f;

#pragma unroll 1
    for (int e = 0; e < 4; ++e) {
        // e1[e] (+gates for e==0)
        if (e == 0) {
            f32x4 acc[4][3] = {};
            gemm_pipe<4, 3, 272, 15, 488>(&sh_x[0][0], wp + OFF_EW1G,
                                          slab[0], slab[1], wave * 32, acc, wave, lane);
#pragma unroll
            for (int j = 0; j < 2; ++j) {
                const int col = wave * 32 + j * 16 + rr;
                const float bv = expb1[col];
#pragma unroll
                for (int i = 0; i < 4; ++i)
#pragma unroll
                    for (int rx = 0; rx < 4; ++rx)
                        sh_c1[i * 16 + g * 4 + rx][col] =
                            (f16)fmaxf(acc[i][j][rx] + bv, 0.f);
            }
            if (wave == 7) {   // gates: logits cols 256..267 -> softmax over e
                const float gb = (rr < 12) ? gateB[rr] : 0.f;
#pragma unroll
                for (int i = 0; i < 4; ++i)
#pragma unroll
                    for (int rx = 0; rx < 4; ++rx) {
                        const float v = acc[i][2][rx] + gb;
                        float m = fmaxf(v, __shfl_xor(v, 1, 64));
                        m = fmaxf(m, __shfl_xor(m, 2, 64));
                        const float p = __expf(v - m);
                        float s = p + __shfl_xor(p, 1, 64);
                        s += __shfl_xor(s, 2, 64);
                        if (rr < 12)
                            sh_g[i * 16 + g * 4 + rx][rr] = p / s;
                    }
            }
        } else {
            f32x4 acc[4][2] = {};
            gemm_pipe<4, 2, 256, 15, 488>(
                &sh_x[0][0], wp + OFF_EW1G + (size_t)(272 + (e - 1) * 256) * 480,
                slab[0], slab[1], wave * 32, acc, wave, lane);
#pragma unroll
            for (int j = 0; j < 2; ++j) {
                const int col = wave * 32 + j * 16 + rr;
                const float bv = expb1[e * 256 + col];
#pragma unroll
                for (int i = 0; i < 4; ++i)
#pragma unroll
                    for (int rx = 0; rx < 4; ++rx)
                        sh_c1[i * 16 + g * 4 + rx][col] =
                            (f16)fmaxf(acc[i][j][rx] + bv, 0.f);
            }
        }
        // e2[e]: eo in regs -> gated per-lane accumulate (reduce deferred)
        {
            f32x4 acc[4][1] = {};
            gemm_pipe<4, 1, 128, 8, 264>(&sh_c1[0][0], wp + OFF_EW2 + (size_t)e * 128 * 256,
                                         slab[0], slab[1], wave * 16, acc, wave, lane);
            const float bv = expb2[e * 128 + wave * 16 + rr];
#pragma unroll
            for (int i = 0; i < 4; ++i)
#pragma unroll
                for (int rx = 0; rx < 4; ++rx) {
                    const int row = i * 16 + g * 4 + rx;
                    const float v = acc[i][0][rx] + bv;
#pragma unroll
                    for (int tt = 0; tt < 3; ++tt)
                        oacc[i][rx][tt] += sh_g[row][tt * 4 + e] * (v * tw[tt]);
                }
        }
    }

    // ---- deferred 16-lane reduce, then cross-wave sum ----
#pragma unroll
    for (int i = 0; i < 4; ++i)
#pragma unroll
        for (int rx = 0; rx < 4; ++rx)
#pragma unroll
            for (int tt = 0; tt < 3; ++tt) {
                float s = oacc[i][rx][tt];
#pragma unroll
                for (int off = 1; off < 16; off <<= 1)
                    s += __shfl_xor(s, off, 64);
                if (rr == 0)
                    sh_part[wave][i * 16 + g * 4 + rx][tt] = s;
            }
    __syncthreads();
    if (t < 64 * 3) {
        const int row = t / 3, tt = t - row * 3;
        float s = taskB[tt];
#pragma unroll
        for (int w = 0; w < 8; ++w) s += sh_part[w][row][tt];
        out[(r0 + row) * 3 + tt] = s;
    }
    if (blockIdx.x == 0 && t < 3) out[(long)BROWS * 3 + t] = logv[t];
}

// ---------------------------------------------------------------------------
extern "C" void kernel_launch(void* const* d_in, const int* in_sizes, int n_in,
                              void* d_out, int out_size, void* d_ws, size_t ws_size,
                              hipStream_t stream)
{
    (void)in_sizes; (void)n_in; (void)out_size; (void)ws_size;

    const int*   disc  = (const int*)  d_in[0];
    const float* cf    = (const float*)d_in[1];
    const float* emb0  = (const float*)d_in[2];
    const float* emb1  = (const float*)d_in[3];
    const float* emb2  = (const float*)d_in[4];
    const float* emb3  = (const float*)d_in[5];
    const float* emb4  = (const float*)d_in[6];
    const float* emb5  = (const float*)d_in[7];
    const float* emb6  = (const float*)d_in[8];
    const float* emb7  = (const float*)d_in[9];
    const float* contW = (const float*)d_in[10];
    const float* contB = (const float*)d_in[11];
    const float* fmW   = (const float*)d_in[12];
    const float* cW1   = (const float*)d_in[13];
    const float* cb1   = (const float*)d_in[14];
    const float* cW2   = (const float*)d_in[15];
    const float* cb2   = (const float*)d_in[16];
    const float* coW   = (const float*)d_in[17];
    const float* cob   = (const float*)d_in[18];
    const float* expW1 = (const float*)d_in[19];
    const float* expb1 = (const float*)d_in[20];
    const float* expW2 = (const float*)d_in[21];
    const float* expb2 = (const float*)d_in[22];
    const float* gateW = (const float*)d_in[23];
    const float* gateB = (const float*)d_in[24];
    const float* taskW = (const float*)d_in[25];
    const float* taskB = (const float*)d_in[26];
    const float* logv  = (const float*)d_in[27];

    f16* wp = (f16*)d_ws;

    pack_all<<<(PACK_TOTAL + 255) / 256, 256, 0, stream>>>(
        cW1, cW2, coW, expW1, expW2, fmW, gateW, contW, wp);

    mmoe_fused<<<BROWS / 64, 512, 0, stream>>>(
        disc, cf, emb0, emb1, emb2, emb3, emb4, emb5, emb6, emb7,
        contB, cb1, cb2, cob, expb1, expb2, gateB, taskW, taskB, logv,
        wp, (float*)d_out);
}